// Round 9
// baseline (340.012 us; speedup 1.0000x reference)
//
#include <hip/hip_runtime.h>
#include <hip/hip_bf16.h>

#define NTOK 2048   // B*S
#define HD   1024
#define FD   3584
#define NE   8

#define BM 128
#define BN1 64              // gemm1 f-tile
#define BN 128              // gemm2 h-tile
#define BK 64               // 128B LDS rows (verified conflict-free layout)
#define NIT1 (HD / BK)      // 16
#define KS2 4               // gemm2 K-split (r9: 2->4 for tail/balance)
#define KLEN2 (FD / KS2)    // 896
#define NIT2 (KLEN2 / BK)   // 14

typedef __attribute__((ext_vector_type(8))) short short8;
typedef __attribute__((ext_vector_type(4))) float f32x4;

__device__ __forceinline__ unsigned short f2bf(float f) {
    __hip_bfloat16 h = __float2bfloat16(f);
    union { __hip_bfloat16 h; unsigned short u; } c; c.h = h;
    return c.u;
}

// global_load_lds width=16: per-lane 16B global src -> wave-uniform LDS base + lane*16
typedef __attribute__((address_space(1))) const unsigned int g_cu32;
typedef __attribute__((address_space(3))) unsigned int l_u32;
__device__ __forceinline__ void gl16(const void* g, void* l) {
    __builtin_amdgcn_global_load_lds((g_cu32*)g, (l_u32*)(unsigned int)(size_t)l, 16, 0, 0);
}

// ---------------- router: fp32 logits, softmax, top-2, renorm ----------------
__global__ void k_router(const float* __restrict__ x, const float* __restrict__ gw,
                         int* __restrict__ sel, float* __restrict__ selw,
                         int* __restrict__ counts) {
    int token = blockIdx.x * 4 + (threadIdx.x >> 6);
    int lane  = threadIdx.x & 63;
    if (token >= NTOK) return;
    const float* xr = x + (size_t)token * HD;
    float acc[NE];
#pragma unroll
    for (int e = 0; e < NE; e++) acc[e] = 0.f;
    for (int h = lane; h < HD; h += 64) {
        float xv = xr[h];
        const float4* g = (const float4*)(gw + (size_t)h * NE);
        float4 g0 = g[0], g1 = g[1];
        acc[0] += xv * g0.x; acc[1] += xv * g0.y; acc[2] += xv * g0.z; acc[3] += xv * g0.w;
        acc[4] += xv * g1.x; acc[5] += xv * g1.y; acc[6] += xv * g1.z; acc[7] += xv * g1.w;
    }
#pragma unroll
    for (int e = 0; e < NE; e++) {
#pragma unroll
        for (int off = 32; off >= 1; off >>= 1) acc[e] += __shfl_xor(acc[e], off, 64);
    }
    if (lane == 0) {
        float m = acc[0];
#pragma unroll
        for (int e = 1; e < NE; e++) m = fmaxf(m, acc[e]);
        float z[NE];
#pragma unroll
        for (int e = 0; e < NE; e++) z[e] = expf(acc[e] - m);
        int e0 = 0; float z0 = z[0];
#pragma unroll
        for (int e = 1; e < NE; e++) if (z[e] > z0) { z0 = z[e]; e0 = e; }
        int e1 = -1; float z1 = -1.f;
#pragma unroll
        for (int e = 0; e < NE; e++) if (e != e0 && z[e] > z1) { z1 = z[e]; e1 = e; }
        float s = z0 + z1;
        sel[token * 2 + 0] = e0; sel[token * 2 + 1] = e1;
        selw[token * 2 + 0] = z0 / s; selw[token * 2 + 1] = z1 / s;
        atomicAdd(&counts[e0], 1);
        atomicAdd(&counts[e1], 1);
    }
}

__global__ void k_scan(const int* __restrict__ counts, int* __restrict__ basep,
                       int* __restrict__ fillc) {
    if (threadIdx.x == 0 && blockIdx.x == 0) {
        int b = 0;
        for (int e = 0; e < NE; e++) { basep[e] = b; b += counts[e]; fillc[e] = 0; }
    }
}

__global__ void k_fill(const int* __restrict__ sel, const float* __restrict__ selw,
                       const int* __restrict__ basep, int* __restrict__ fillc,
                       int* __restrict__ rowmap, int* __restrict__ rowk,
                       float* __restrict__ roww) {
    int n = blockIdx.x * blockDim.x + threadIdx.x;
    if (n >= NTOK) return;
#pragma unroll
    for (int k = 0; k < 2; k++) {
        int e = sel[n * 2 + k];
        int p = atomicAdd(&fillc[e], 1);
        int g = basep[e] + p;
        rowmap[g] = n; rowk[g] = k; roww[g] = selw[n * 2 + k];
    }
}

// ---------------- x -> bf16 ----------------
__global__ void k_cvt(const float* __restrict__ x, unsigned short* __restrict__ xb) {
    size_t i = ((size_t)blockIdx.x * blockDim.x + threadIdx.x) * 8;
    float4 a = *(const float4*)(x + i);
    float4 b = *(const float4*)(x + i + 4);
    unsigned short p[8] __attribute__((aligned(16))) =
        { f2bf(a.x), f2bf(a.y), f2bf(a.z), f2bf(a.w),
          f2bf(b.x), f2bf(b.y), f2bf(b.z), f2bf(b.w) };
    *(uint4*)(xb + i) = *(uint4*)p;
}

// ---------------- weight transpose+convert: [E][K][N] f32 -> [E][N][K] bf16 ----------------
__global__ void k_wt(const float* __restrict__ w, unsigned short* __restrict__ wt,
                     int K, int N) {
    __shared__ unsigned short tile[64][66];
    const int t = threadIdx.x;
    const float* src = w + (size_t)blockIdx.z * K * N + ((size_t)blockIdx.y * 64) * N + blockIdx.x * 64;
    {
        const int r = t >> 4;
        const int c4 = (t & 15) * 4;
#pragma unroll
        for (int i = 0; i < 4; i++) {
            const int kr = r + i * 16;
            float4 v = *(const float4*)(src + (size_t)kr * N + c4);
            unsigned short p[4] = { f2bf(v.x), f2bf(v.y), f2bf(v.z), f2bf(v.w) };
            *(unsigned int*)&tile[kr][c4]     = *(unsigned int*)&p[0];
            *(unsigned int*)&tile[kr][c4 + 2] = *(unsigned int*)&p[2];
        }
    }
    __syncthreads();
    unsigned short* dst = wt + (size_t)blockIdx.z * N * K + ((size_t)blockIdx.x * 64) * K + blockIdx.y * 64;
    const int n = t >> 3;
    const int kc = (t & 7) * 8;
#pragma unroll
    for (int i = 0; i < 2; i++) {
        const int nn = n + i * 32;
        unsigned short p[8] __attribute__((aligned(16)));
#pragma unroll
        for (int j = 0; j < 8; j++) p[j] = tile[kc + j][nn];
        *(uint4*)&dst[(size_t)nn * K + kc] = *(uint4*)p;
    }
}

// ---------------- GEMM1: act = silu(X@W1)*(X@W3); BK=64, dbuf, counted vmcnt ----------------
// LDS: 2 x (128 + 64 + 64) x 128B = 64KB -> 2 blocks/CU at 512 thr (16 waves/CU).
__global__ __launch_bounds__(512, 4) void k_gemm1(
    const unsigned short* __restrict__ xb,
    const unsigned short* __restrict__ w1t, const unsigned short* __restrict__ w3t,
    const int* __restrict__ counts, const int* __restrict__ basep,
    const int* __restrict__ rowmap, unsigned short* __restrict__ act)
{
    const int e = blockIdx.z;
    const int nrows = counts[e];
    const int m0 = blockIdx.y * BM;
    if (m0 >= nrows) return;
    const int f0 = blockIdx.x * BN1;
    const int gbase = basep[e];

    __shared__ __align__(16) unsigned short At[2][BM][BK];
    __shared__ __align__(16) unsigned short B1[2][BN1][BK];
    __shared__ __align__(16) unsigned short B3[2][BN1][BK];

    const int t = threadIdx.x;
    const int lane = t & 63;
    const int w = t >> 6;                 // 0..7
    const int wrm = w >> 1, wnn = w & 1;  // 4m x 2n wave grid; wave tile 32 x 32
    const int lr = lane >> 3;
    const int so = ((lane & 7) ^ lr) * 8; // verified swizzle: chunk ^ (row&7)

    const unsigned short* asrc[2];
#pragma unroll
    for (int c = 0; c < 2; c++) {
        const int row = (w * 2 + c) * 8 + lr;
        const int tok = rowmap[gbase + min(m0 + row, nrows - 1)];
        asrc[c] = xb + (size_t)tok * HD + so;
    }
    const int brow = w * 8 + lr;
    const unsigned short* b1src = w1t + ((size_t)(e * FD + f0 + brow)) * HD + so;
    const unsigned short* b3src = w3t + ((size_t)(e * FD + f0 + brow)) * HD + so;

    f32x4 acc1[2][2], acc3[2][2];
#pragma unroll
    for (int i = 0; i < 2; i++)
#pragma unroll
        for (int j = 0; j < 2; j++) { acc1[i][j] = (f32x4)(0.f); acc3[i][j] = (f32x4)(0.f); }

    const int l15 = lane & 15;
    const int lhi = lane >> 4;
    const int rs = (l15 & 7) * 8;

    // prologue: stage k-tile 0 into buf 0 (4 loads/thread in flight)
#pragma unroll
    for (int c = 0; c < 2; c++) gl16(asrc[c], &At[0][(w * 2 + c) * 8][0]);
    gl16(b1src, &B1[0][w * 8][0]);
    gl16(b3src, &B3[0][w * 8][0]);

    for (int it = 0; it < NIT1; ++it) {
        const int cur = it & 1;
        // issue next tile's loads, then wait ONLY for the current tile's loads
        // (issued one iteration ago): counted vmcnt(4) keeps next tile in flight.
        if (it + 1 < NIT1) {
            const int kn = (it + 1) * BK;
#pragma unroll
            for (int c = 0; c < 2; c++) gl16(asrc[c] + kn, &At[cur ^ 1][(w * 2 + c) * 8][0]);
            gl16(b1src + kn, &B1[cur ^ 1][w * 8][0]);
            gl16(b3src + kn, &B3[cur ^ 1][w * 8][0]);
            asm volatile("s_waitcnt vmcnt(4)" ::: "memory");
        } else {
            asm volatile("s_waitcnt vmcnt(0)" ::: "memory");
        }
        __builtin_amdgcn_s_barrier();   // tile `cur` ready in all waves' LDS rows
#pragma unroll
        for (int kk = 0; kk < 2; kk++) {
            const int kc = (kk * 32 + lhi * 8) ^ rs;
            short8 af[2], b1f[2], b3f[2];
#pragma unroll
            for (int i = 0; i < 2; i++)
                af[i] = *(const short8*)&At[cur][wrm * 32 + i * 16 + l15][kc];
#pragma unroll
            for (int j = 0; j < 2; j++) {
                b1f[j] = *(const short8*)&B1[cur][wnn * 32 + j * 16 + l15][kc];
                b3f[j] = *(const short8*)&B3[cur][wnn * 32 + j * 16 + l15][kc];
            }
#pragma unroll
            for (int i = 0; i < 2; i++)
#pragma unroll
                for (int j = 0; j < 2; j++) {
                    acc1[i][j] = __builtin_amdgcn_mfma_f32_16x16x32_bf16(af[i], b1f[j], acc1[i][j], 0, 0, 0);
                    acc3[i][j] = __builtin_amdgcn_mfma_f32_16x16x32_bf16(af[i], b3f[j], acc3[i][j], 0, 0, 0);
                }
        }
        __builtin_amdgcn_s_barrier();   // readers done before next-iter overwrite
    }

    // epilogue: SwiGLU, bf16 act
    const int rbase = wrm * 32 + lhi * 4;
    const int cbase = f0 + wnn * 32 + l15;
#pragma unroll
    for (int i = 0; i < 2; i++) {
#pragma unroll
        for (int r = 0; r < 4; r++) {
            const int ml = rbase + i * 16 + r;
            if (m0 + ml < nrows) {
                const size_t rowoff = (size_t)(gbase + m0 + ml) * FD;
#pragma unroll
                for (int j = 0; j < 2; j++) {
                    float y1 = acc1[i][j][r];
                    float y3 = acc3[i][j][r];
                    float sv = (y1 / (1.f + __expf(-y1))) * y3;
                    act[rowoff + cbase + j * 16] = f2bf(sv);
                }
            }
        }
    }
}

// ---------------- GEMM2: K-split x4, dbuf, counted vmcnt ----------------
__global__ __launch_bounds__(512, 4) void k_gemm2(
    const unsigned short* __restrict__ act,
    const unsigned short* __restrict__ w2t,
    const int* __restrict__ counts, const int* __restrict__ basep,
    const int* __restrict__ rowmap, const int* __restrict__ rowk,
    const float* __restrict__ roww, float* __restrict__ partial)
{
    const int z = blockIdx.z;
    const int e = z >> 2, ks = z & 3;     // KS2=4
    const int nrows = counts[e];
    const int m0 = blockIdx.y * BM;
    if (m0 >= nrows) return;
    const int h0 = blockIdx.x * BN;
    const int gbase = basep[e];
    const int kbase = ks * KLEN2;

    __shared__ __align__(16) unsigned short At[2][BM][BK];
    __shared__ __align__(16) unsigned short Bt[2][BN][BK];

    const int t = threadIdx.x;
    const int lane = t & 63;
    const int w = t >> 6;
    const int wr = w >> 2, wn = w & 3;    // 2m x 4n; wave tile 64 x 32
    const int lr = lane >> 3;
    const int so = ((lane & 7) ^ lr) * 8;

    const unsigned short* asrc[2];
    const unsigned short* bsrc[2];
#pragma unroll
    for (int c = 0; c < 2; c++) {
        const int row = (w * 2 + c) * 8 + lr;
        asrc[c] = act + ((size_t)gbase + min(m0 + row, nrows - 1)) * FD + so + kbase;
        bsrc[c] = w2t + ((size_t)(e * HD + h0 + row)) * FD + so + kbase;
    }

    f32x4 acc[4][2];
#pragma unroll
    for (int i = 0; i < 4; i++)
#pragma unroll
        for (int j = 0; j < 2; j++) acc[i][j] = (f32x4)(0.f);

    const int l15 = lane & 15;
    const int lhi = lane >> 4;
    const int rs = (l15 & 7) * 8;

    // prologue: stage tile 0 into buf 0 (4 loads/thread)
#pragma unroll
    for (int c = 0; c < 2; c++) {
        gl16(asrc[c], &At[0][(w * 2 + c) * 8][0]);
        gl16(bsrc[c], &Bt[0][(w * 2 + c) * 8][0]);
    }

    for (int it = 0; it < NIT2; ++it) {
        const int cur = it & 1;
        if (it + 1 < NIT2) {
            const int kn = (it + 1) * BK;
#pragma unroll
            for (int c = 0; c < 2; c++) {
                gl16(asrc[c] + kn, &At[cur ^ 1][(w * 2 + c) * 8][0]);
                gl16(bsrc[c] + kn, &Bt[cur ^ 1][(w * 2 + c) * 8][0]);
            }
            asm volatile("s_waitcnt vmcnt(4)" ::: "memory");
        } else {
            asm volatile("s_waitcnt vmcnt(0)" ::: "memory");
        }
        __builtin_amdgcn_s_barrier();
#pragma unroll
        for (int kk = 0; kk < 2; kk++) {
            const int kc = (kk * 32 + lhi * 8) ^ rs;
            short8 af[4], bf[2];
#pragma unroll
            for (int i = 0; i < 4; i++)
                af[i] = *(const short8*)&At[cur][wr * 64 + i * 16 + l15][kc];
#pragma unroll
            for (int j = 0; j < 2; j++)
                bf[j] = *(const short8*)&Bt[cur][wn * 32 + j * 16 + l15][kc];
#pragma unroll
            for (int i = 0; i < 4; i++)
#pragma unroll
                for (int j = 0; j < 2; j++)
                    acc[i][j] = __builtin_amdgcn_mfma_f32_16x16x32_bf16(af[i], bf[j], acc[i][j], 0, 0, 0);
        }
        __builtin_amdgcn_s_barrier();
    }

    const int rbase = wr * 64 + lhi * 4;
    const int cbase = h0 + wn * 32 + l15;
#pragma unroll
    for (int i = 0; i < 4; i++) {
#pragma unroll
        for (int r = 0; r < 4; r++) {
            const int ml = rbase + i * 16 + r;
            if (m0 + ml < nrows) {
                const int grow = gbase + m0 + ml;
                const int tok = rowmap[grow];
                const int slot = rowk[grow];
                const float wv = roww[grow];
                float* op = partial + (((size_t)slot * KS2 + ks) * NTOK + tok) * HD + cbase;
#pragma unroll
                for (int j = 0; j < 2; j++) op[j * 16] = acc[i][j][r] * wv;
            }
        }
    }
}

__global__ void k_combine(const float* __restrict__ partial, float* __restrict__ out) {
    size_t i = ((size_t)blockIdx.x * blockDim.x + threadIdx.x) * 4;
    const size_t st = (size_t)NTOK * HD;
    float4 o = *(const float4*)(partial + i);
#pragma unroll
    for (int s = 1; s < 2 * KS2; s++) {
        float4 v = *(const float4*)(partial + (size_t)s * st + i);
        o.x += v.x; o.y += v.y; o.z += v.z; o.w += v.w;
    }
    *(float4*)(out + i) = o;
}

extern "C" void kernel_launch(void* const* d_in, const int* in_sizes, int n_in,
                              void* d_out, int out_size, void* d_ws, size_t ws_size,
                              hipStream_t stream) {
    const float* x  = (const float*)d_in[0];
    const float* gw = (const float*)d_in[1];
    const float* w1 = (const float*)d_in[2];
    const float* w3 = (const float*)d_in[3];
    const float* w2 = (const float*)d_in[4];
    float* out = (float*)d_out;

    char* ws = (char*)d_ws;
    size_t off = 0;
    auto alloc = [&](size_t b) { char* p = ws + off; off += (b + 255) & ~(size_t)255; return p; };
    int*   sel    = (int*)  alloc((size_t)NTOK * 2 * 4);
    float* selw   = (float*)alloc((size_t)NTOK * 2 * 4);
    int*   counts = (int*)  alloc(NE * 4);
    int*   basep  = (int*)  alloc(NE * 4);
    int*   fillc  = (int*)  alloc(NE * 4);
    int*   rowmap = (int*)  alloc((size_t)NTOK * 2 * 4);
    int*   rowk   = (int*)  alloc((size_t)NTOK * 2 * 4);
    float* roww   = (float*)alloc((size_t)NTOK * 2 * 4);
    unsigned short* xb  = (unsigned short*)alloc((size_t)NTOK * HD * 2);
    unsigned short* act = (unsigned short*)alloc((size_t)NTOK * 2 * FD * 2);
    unsigned short* w1t = (unsigned short*)alloc((size_t)NE * HD * FD * 2);
    unsigned short* w3t = (unsigned short*)alloc((size_t)NE * HD * FD * 2);
    unsigned short* w2t = (unsigned short*)alloc((size_t)NE * HD * FD * 2);
    // partial (2*KS2=8 x NTOK x HD f32 = 67 MB) aliases the w1t+w3t region
    // (117 MB contiguous): both are dead after k_gemm1; partial is written in
    // k_gemm2 and read in k_combine.
    float* partial = (float*)w1t;

    hipMemsetAsync(counts, 0, NE * 4, stream);
    // weight convert+transpose: [E][K][N] f32 -> [E][N][K] bf16
    k_wt<<<dim3(FD / 64, HD / 64, NE), 256, 0, stream>>>(w1, w1t, HD, FD);
    k_wt<<<dim3(FD / 64, HD / 64, NE), 256, 0, stream>>>(w3, w3t, HD, FD);
    k_wt<<<dim3(HD / 64, FD / 64, NE), 256, 0, stream>>>(w2, w2t, FD, HD);
    k_cvt<<<(NTOK * HD) / (256 * 8), 256, 0, stream>>>(x, xb);
    k_router<<<NTOK / 4, 256, 0, stream>>>(x, gw, sel, selw, counts);
    k_scan<<<1, 64, 0, stream>>>(counts, basep, fillc);
    k_fill<<<NTOK / 256, 256, 0, stream>>>(sel, selw, basep, fillc, rowmap, rowk, roww);
    k_gemm1<<<dim3(FD / BN1, NTOK / BM, NE), 512, 0, stream>>>(xb, w1t, w3t, counts, basep, rowmap, act);
    k_gemm2<<<dim3(HD / BN, NTOK / BM, NE * KS2), 512, 0, stream>>>(act, w2t, counts, basep, rowmap, rowk, roww, partial);
    k_combine<<<(NTOK * HD) / (256 * 4), 256, 0, stream>>>(partial, out);
}

// Round 10
// 330.579 us; speedup vs baseline: 1.0285x; 1.0285x over previous
//
#include <hip/hip_runtime.h>
#include <hip/hip_bf16.h>

#define NTOK 2048   // B*S
#define HD   1024
#define FD   3584
#define NE   8

#define BM 128              // gemm1 m-tile
#define BN1 64              // gemm1 f-tile
#define BM2 64              // gemm2 m-tile
#define BN 128              // gemm2 h-tile
#define BK 64               // 128B LDS rows (verified conflict-free layout)
#define NIT1 (HD / BK)      // 16
#define KS2 2               // gemm2 K-split
#define KLEN2 (FD / KS2)    // 1792
#define NIT2 (KLEN2 / BK)   // 28

typedef __attribute__((ext_vector_type(8))) short short8;
typedef __attribute__((ext_vector_type(4))) float f32x4;

__device__ __forceinline__ unsigned short f2bf(float f) {
    __hip_bfloat16 h = __float2bfloat16(f);
    union { __hip_bfloat16 h; unsigned short u; } c; c.h = h;
    return c.u;
}

// global_load_lds width=16: per-lane 16B global src -> wave-uniform LDS base + lane*16
typedef __attribute__((address_space(1))) const unsigned int g_cu32;
typedef __attribute__((address_space(3))) unsigned int l_u32;
__device__ __forceinline__ void gl16(const void* g, void* l) {
    __builtin_amdgcn_global_load_lds((g_cu32*)g, (l_u32*)(unsigned int)(size_t)l, 16, 0, 0);
}

// ---------------- router: fp32 logits, softmax, top-2, renorm ----------------
__global__ void k_router(const float* __restrict__ x, const float* __restrict__ gw,
                         int* __restrict__ sel, float* __restrict__ selw,
                         int* __restrict__ counts) {
    int token = blockIdx.x * 4 + (threadIdx.x >> 6);
    int lane  = threadIdx.x & 63;
    if (token >= NTOK) return;
    const float* xr = x + (size_t)token * HD;
    float acc[NE];
#pragma unroll
    for (int e = 0; e < NE; e++) acc[e] = 0.f;
    for (int h = lane; h < HD; h += 64) {
        float xv = xr[h];
        const float4* g = (const float4*)(gw + (size_t)h * NE);
        float4 g0 = g[0], g1 = g[1];
        acc[0] += xv * g0.x; acc[1] += xv * g0.y; acc[2] += xv * g0.z; acc[3] += xv * g0.w;
        acc[4] += xv * g1.x; acc[5] += xv * g1.y; acc[6] += xv * g1.z; acc[7] += xv * g1.w;
    }
#pragma unroll
    for (int e = 0; e < NE; e++) {
#pragma unroll
        for (int off = 32; off >= 1; off >>= 1) acc[e] += __shfl_xor(acc[e], off, 64);
    }
    if (lane == 0) {
        float m = acc[0];
#pragma unroll
        for (int e = 1; e < NE; e++) m = fmaxf(m, acc[e]);
        float z[NE];
#pragma unroll
        for (int e = 0; e < NE; e++) z[e] = expf(acc[e] - m);
        int e0 = 0; float z0 = z[0];
#pragma unroll
        for (int e = 1; e < NE; e++) if (z[e] > z0) { z0 = z[e]; e0 = e; }
        int e1 = -1; float z1 = -1.f;
#pragma unroll
        for (int e = 0; e < NE; e++) if (e != e0 && z[e] > z1) { z1 = z[e]; e1 = e; }
        float s = z0 + z1;
        sel[token * 2 + 0] = e0; sel[token * 2 + 1] = e1;
        selw[token * 2 + 0] = z0 / s; selw[token * 2 + 1] = z1 / s;
        atomicAdd(&counts[e0], 1);
        atomicAdd(&counts[e1], 1);
    }
}

__global__ void k_scan(const int* __restrict__ counts, int* __restrict__ basep,
                       int* __restrict__ fillc) {
    if (threadIdx.x == 0 && blockIdx.x == 0) {
        int b = 0;
        for (int e = 0; e < NE; e++) { basep[e] = b; b += counts[e]; fillc[e] = 0; }
    }
}

__global__ void k_fill(const int* __restrict__ sel, const float* __restrict__ selw,
                       const int* __restrict__ basep, int* __restrict__ fillc,
                       int* __restrict__ rowmap, int* __restrict__ rowk,
                       float* __restrict__ roww) {
    int n = blockIdx.x * blockDim.x + threadIdx.x;
    if (n >= NTOK) return;
#pragma unroll
    for (int k = 0; k < 2; k++) {
        int e = sel[n * 2 + k];
        int p = atomicAdd(&fillc[e], 1);
        int g = basep[e] + p;
        rowmap[g] = n; rowk[g] = k; roww[g] = selw[n * 2 + k];
    }
}

// ---------------- x -> bf16 ----------------
__global__ void k_cvt(const float* __restrict__ x, unsigned short* __restrict__ xb) {
    size_t i = ((size_t)blockIdx.x * blockDim.x + threadIdx.x) * 8;
    float4 a = *(const float4*)(x + i);
    float4 b = *(const float4*)(x + i + 4);
    unsigned short p[8] __attribute__((aligned(16))) =
        { f2bf(a.x), f2bf(a.y), f2bf(a.z), f2bf(a.w),
          f2bf(b.x), f2bf(b.y), f2bf(b.z), f2bf(b.w) };
    *(uint4*)(xb + i) = *(uint4*)p;
}

// ---------------- fused weight transpose+convert: all 3 weights, one launch ----------------
// z<8: w1 (K=HD,N=FD); z<16: w3; z>=16: w2 (K=FD,N=HD). 896 tiles per slab.
__global__ void k_wt3(const float* __restrict__ w1, const float* __restrict__ w3,
                      const float* __restrict__ w2,
                      unsigned short* __restrict__ w1t, unsigned short* __restrict__ w3t,
                      unsigned short* __restrict__ w2t) {
    __shared__ unsigned short tile[64][66];
    const int z = blockIdx.z;
    int K, N, tx, ty;
    const float* src;
    unsigned short* dst;
    if (z < 16) {
        K = HD; N = FD;
        const int e = z & 7;
        src = (z < 8 ? w1 : w3) + (size_t)e * K * N;
        dst = (z < 8 ? w1t : w3t) + (size_t)e * N * K;
        tx = blockIdx.x % (FD / 64); ty = blockIdx.x / (FD / 64);
    } else {
        K = FD; N = HD;
        const int e = z - 16;
        src = w2 + (size_t)e * K * N;
        dst = w2t + (size_t)e * N * K;
        tx = blockIdx.x % (HD / 64); ty = blockIdx.x / (HD / 64);
    }
    src += (size_t)(ty * 64) * N + tx * 64;
    dst += (size_t)(tx * 64) * K + ty * 64;

    const int t = threadIdx.x;
    {
        const int r = t >> 4;
        const int c4 = (t & 15) * 4;
#pragma unroll
        for (int i = 0; i < 4; i++) {
            const int kr = r + i * 16;
            float4 v = *(const float4*)(src + (size_t)kr * N + c4);
            unsigned short p[4] = { f2bf(v.x), f2bf(v.y), f2bf(v.z), f2bf(v.w) };
            *(unsigned int*)&tile[kr][c4]     = *(unsigned int*)&p[0];
            *(unsigned int*)&tile[kr][c4 + 2] = *(unsigned int*)&p[2];
        }
    }
    __syncthreads();
    const int n = t >> 3;
    const int kc = (t & 7) * 8;
#pragma unroll
    for (int i = 0; i < 2; i++) {
        const int nn = n + i * 32;
        unsigned short p[8] __attribute__((aligned(16)));
#pragma unroll
        for (int j = 0; j < 8; j++) p[j] = tile[kc + j][nn];
        *(uint4*)&dst[(size_t)nn * K + kc] = *(uint4*)p;
    }
}

// ---------------- GEMM1: 256 thr, 4 waves 2x2, wave tile 64x32 ----------------
// LDS reads per kk: af[4]+b1f[2]+b3f[2] = 8 for 16 MFMAs (1:2, was 3:4).
// LDS 64KB dbuf -> 2 blocks/CU (8 waves). (256,2): no VGPR cap pressure.
__global__ __launch_bounds__(256, 2) void k_gemm1(
    const unsigned short* __restrict__ xb,
    const unsigned short* __restrict__ w1t, const unsigned short* __restrict__ w3t,
    const int* __restrict__ counts, const int* __restrict__ basep,
    const int* __restrict__ rowmap, unsigned short* __restrict__ act)
{
    const int e = blockIdx.z;
    const int nrows = counts[e];
    const int m0 = blockIdx.y * BM;
    if (m0 >= nrows) return;
    const int f0 = blockIdx.x * BN1;
    const int gbase = basep[e];

    __shared__ __align__(16) unsigned short At[2][BM][BK];
    __shared__ __align__(16) unsigned short B1[2][BN1][BK];
    __shared__ __align__(16) unsigned short B3[2][BN1][BK];

    const int t = threadIdx.x;
    const int lane = t & 63;
    const int w = t >> 6;                 // 0..3
    const int wrm = w >> 1, wnn = w & 1;  // 2x2 wave grid; wave tile 64 x 32
    const int lr = lane >> 3;
    const int so = ((lane & 7) ^ lr) * 8; // verified swizzle: chunk ^ (row&7)

    const unsigned short* asrc[4];
#pragma unroll
    for (int c = 0; c < 4; c++) {
        const int row = (w * 4 + c) * 8 + lr;
        const int tok = rowmap[gbase + min(m0 + row, nrows - 1)];
        asrc[c] = xb + (size_t)tok * HD + so;
    }
    const unsigned short* b1src[2];
    const unsigned short* b3src[2];
#pragma unroll
    for (int c = 0; c < 2; c++) {
        const int row = (w * 2 + c) * 8 + lr;
        b1src[c] = w1t + ((size_t)(e * FD + f0 + row)) * HD + so;
        b3src[c] = w3t + ((size_t)(e * FD + f0 + row)) * HD + so;
    }

    f32x4 acc1[4][2], acc3[4][2];
#pragma unroll
    for (int i = 0; i < 4; i++)
#pragma unroll
        for (int j = 0; j < 2; j++) { acc1[i][j] = (f32x4)(0.f); acc3[i][j] = (f32x4)(0.f); }

    const int l15 = lane & 15;
    const int lhi = lane >> 4;
    const int rs = (l15 & 7) * 8;

    // prologue: stage k-tile 0 into buf 0 (8 loads/thread in flight)
#pragma unroll
    for (int c = 0; c < 4; c++) gl16(asrc[c], &At[0][(w * 4 + c) * 8][0]);
#pragma unroll
    for (int c = 0; c < 2; c++) {
        gl16(b1src[c], &B1[0][(w * 2 + c) * 8][0]);
        gl16(b3src[c], &B3[0][(w * 2 + c) * 8][0]);
    }

    for (int it = 0; it < NIT1; ++it) {
        const int cur = it & 1;
        if (it + 1 < NIT1) {
            const int kn = (it + 1) * BK;
#pragma unroll
            for (int c = 0; c < 4; c++) gl16(asrc[c] + kn, &At[cur ^ 1][(w * 4 + c) * 8][0]);
#pragma unroll
            for (int c = 0; c < 2; c++) {
                gl16(b1src[c] + kn, &B1[cur ^ 1][(w * 2 + c) * 8][0]);
                gl16(b3src[c] + kn, &B3[cur ^ 1][(w * 2 + c) * 8][0]);
            }
            asm volatile("s_waitcnt vmcnt(8)" ::: "memory");   // wait current tile only
        } else {
            asm volatile("s_waitcnt vmcnt(0)" ::: "memory");
        }
        __builtin_amdgcn_s_barrier();
#pragma unroll
        for (int kk = 0; kk < 2; kk++) {
            const int kc = (kk * 32 + lhi * 8) ^ rs;
            short8 af[4], b1f[2], b3f[2];
#pragma unroll
            for (int i = 0; i < 4; i++)
                af[i] = *(const short8*)&At[cur][wrm * 64 + i * 16 + l15][kc];
#pragma unroll
            for (int j = 0; j < 2; j++) {
                b1f[j] = *(const short8*)&B1[cur][wnn * 32 + j * 16 + l15][kc];
                b3f[j] = *(const short8*)&B3[cur][wnn * 32 + j * 16 + l15][kc];
            }
#pragma unroll
            for (int i = 0; i < 4; i++)
#pragma unroll
                for (int j = 0; j < 2; j++) {
                    acc1[i][j] = __builtin_amdgcn_mfma_f32_16x16x32_bf16(af[i], b1f[j], acc1[i][j], 0, 0, 0);
                    acc3[i][j] = __builtin_amdgcn_mfma_f32_16x16x32_bf16(af[i], b3f[j], acc3[i][j], 0, 0, 0);
                }
        }
        __builtin_amdgcn_s_barrier();
    }

    // epilogue: SwiGLU, bf16 act
    const int rbase = wrm * 64 + lhi * 4;
    const int cbase = f0 + wnn * 32 + l15;
#pragma unroll
    for (int i = 0; i < 4; i++) {
#pragma unroll
        for (int r = 0; r < 4; r++) {
            const int ml = rbase + i * 16 + r;
            if (m0 + ml < nrows) {
                const size_t rowoff = (size_t)(gbase + m0 + ml) * FD;
#pragma unroll
                for (int j = 0; j < 2; j++) {
                    float y1 = acc1[i][j][r];
                    float y3 = acc3[i][j][r];
                    float sv = (y1 / (1.f + __expf(-y1))) * y3;
                    act[rowoff + cbase + j * 16] = f2bf(sv);
                }
            }
        }
    }
}

// ---------------- GEMM2: BM2=64 x BN=128, 256 thr, wave tile 32x64, K-split x2 ----------------
// LDS reads per kk: af[2]+bf[4] = 6 for 16 MFMAs (3:8, was 3:4). 48KB -> 3 blocks/CU.
__global__ __launch_bounds__(256, 4) void k_gemm2(
    const unsigned short* __restrict__ act,
    const unsigned short* __restrict__ w2t,
    const int* __restrict__ counts, const int* __restrict__ basep,
    const int* __restrict__ rowmap, const int* __restrict__ rowk,
    const float* __restrict__ roww, float* __restrict__ partial)
{
    const int z = blockIdx.z;
    const int e = z >> 1, ks = z & 1;
    const int nrows = counts[e];
    const int m0 = blockIdx.y * BM2;
    if (m0 >= nrows) return;
    const int h0 = blockIdx.x * BN;
    const int gbase = basep[e];
    const int kbase = ks * KLEN2;

    __shared__ __align__(16) unsigned short At[2][BM2][BK];
    __shared__ __align__(16) unsigned short Bt[2][BN][BK];

    const int t = threadIdx.x;
    const int lane = t & 63;
    const int w = t >> 6;                 // 0..3
    const int wr2 = w >> 1, wn2 = w & 1;  // 2x2; wave tile 32 x 64
    const int lr = lane >> 3;
    const int so = ((lane & 7) ^ lr) * 8;

    const unsigned short* asrc[2];
#pragma unroll
    for (int c = 0; c < 2; c++) {
        const int row = (w * 2 + c) * 8 + lr;
        asrc[c] = act + ((size_t)gbase + min(m0 + row, nrows - 1)) * FD + so + kbase;
    }
    const unsigned short* bsrc[4];
#pragma unroll
    for (int c = 0; c < 4; c++) {
        const int row = (w * 4 + c) * 8 + lr;
        bsrc[c] = w2t + ((size_t)(e * HD + h0 + row)) * FD + so + kbase;
    }

    f32x4 acc[2][4];
#pragma unroll
    for (int i = 0; i < 2; i++)
#pragma unroll
        for (int j = 0; j < 4; j++) acc[i][j] = (f32x4)(0.f);

    const int l15 = lane & 15;
    const int lhi = lane >> 4;
    const int rs = (l15 & 7) * 8;

    // prologue: stage tile 0 into buf 0 (6 loads/thread)
#pragma unroll
    for (int c = 0; c < 2; c++) gl16(asrc[c], &At[0][(w * 2 + c) * 8][0]);
#pragma unroll
    for (int c = 0; c < 4; c++) gl16(bsrc[c], &Bt[0][(w * 4 + c) * 8][0]);

    for (int it = 0; it < NIT2; ++it) {
        const int cur = it & 1;
        if (it + 1 < NIT2) {
            const int kn = (it + 1) * BK;
#pragma unroll
            for (int c = 0; c < 2; c++) gl16(asrc[c] + kn, &At[cur ^ 1][(w * 2 + c) * 8][0]);
#pragma unroll
            for (int c = 0; c < 4; c++) gl16(bsrc[c] + kn, &Bt[cur ^ 1][(w * 4 + c) * 8][0]);
            asm volatile("s_waitcnt vmcnt(6)" ::: "memory");
        } else {
            asm volatile("s_waitcnt vmcnt(0)" ::: "memory");
        }
        __builtin_amdgcn_s_barrier();
#pragma unroll
        for (int kk = 0; kk < 2; kk++) {
            const int kc = (kk * 32 + lhi * 8) ^ rs;
            short8 af[2], bf[4];
#pragma unroll
            for (int i = 0; i < 2; i++)
                af[i] = *(const short8*)&At[cur][wr2 * 32 + i * 16 + l15][kc];
#pragma unroll
            for (int j = 0; j < 4; j++)
                bf[j] = *(const short8*)&Bt[cur][wn2 * 64 + j * 16 + l15][kc];
#pragma unroll
            for (int i = 0; i < 2; i++)
#pragma unroll
                for (int j = 0; j < 4; j++)
                    acc[i][j] = __builtin_amdgcn_mfma_f32_16x16x32_bf16(af[i], bf[j], acc[i][j], 0, 0, 0);
        }
        __builtin_amdgcn_s_barrier();
    }

    const int rbase = wr2 * 32 + lhi * 4;
    const int cbase = h0 + wn2 * 64 + l15;
#pragma unroll
    for (int i = 0; i < 2; i++) {
#pragma unroll
        for (int r = 0; r < 4; r++) {
            const int ml = rbase + i * 16 + r;
            if (m0 + ml < nrows) {
                const int grow = gbase + m0 + ml;
                const int tok = rowmap[grow];
                const int slot = rowk[grow];
                const float wv = roww[grow];
                float* op = partial + (((size_t)slot * KS2 + ks) * NTOK + tok) * HD + cbase;
#pragma unroll
                for (int j = 0; j < 4; j++) op[j * 16] = acc[i][j][r] * wv;
            }
        }
    }
}

__global__ void k_combine(const float* __restrict__ partial, float* __restrict__ out) {
    size_t i = ((size_t)blockIdx.x * blockDim.x + threadIdx.x) * 4;
    const size_t st = (size_t)NTOK * HD;
    float4 o = *(const float4*)(partial + i);
#pragma unroll
    for (int s = 1; s < 2 * KS2; s++) {
        float4 v = *(const float4*)(partial + (size_t)s * st + i);
        o.x += v.x; o.y += v.y; o.z += v.z; o.w += v.w;
    }
    *(float4*)(out + i) = o;
}

extern "C" void kernel_launch(void* const* d_in, const int* in_sizes, int n_in,
                              void* d_out, int out_size, void* d_ws, size_t ws_size,
                              hipStream_t stream) {
    const float* x  = (const float*)d_in[0];
    const float* gw = (const float*)d_in[1];
    const float* w1 = (const float*)d_in[2];
    const float* w3 = (const float*)d_in[3];
    const float* w2 = (const float*)d_in[4];
    float* out = (float*)d_out;

    char* ws = (char*)d_ws;
    size_t off = 0;
    auto alloc = [&](size_t b) { char* p = ws + off; off += (b + 255) & ~(size_t)255; return p; };
    int*   sel    = (int*)  alloc((size_t)NTOK * 2 * 4);
    float* selw   = (float*)alloc((size_t)NTOK * 2 * 4);
    int*   counts = (int*)  alloc(NE * 4);
    int*   basep  = (int*)  alloc(NE * 4);
    int*   fillc  = (int*)  alloc(NE * 4);
    int*   rowmap = (int*)  alloc((size_t)NTOK * 2 * 4);
    int*   rowk   = (int*)  alloc((size_t)NTOK * 2 * 4);
    float* roww   = (float*)alloc((size_t)NTOK * 2 * 4);
    unsigned short* xb  = (unsigned short*)alloc((size_t)NTOK * HD * 2);
    unsigned short* act = (unsigned short*)alloc((size_t)NTOK * 2 * FD * 2);
    unsigned short* w1t = (unsigned short*)alloc((size_t)NE * HD * FD * 2);
    unsigned short* w3t = (unsigned short*)alloc((size_t)NE * HD * FD * 2);
    unsigned short* w2t = (unsigned short*)alloc((size_t)NE * HD * FD * 2);
    // partial (2*KS2=4 x NTOK x HD f32 = 33.6 MB) aliases w1t's region (58.7 MB):
    // w1t is dead after k_gemm1; partial is written in k_gemm2, read in k_combine.
    float* partial = (float*)w1t;

    hipMemsetAsync(counts, 0, NE * 4, stream);
    k_wt3<<<dim3(896, 1, 24), 256, 0, stream>>>(w1, w3, w2, w1t, w3t, w2t);
    k_cvt<<<(NTOK * HD) / (256 * 8), 256, 0, stream>>>(x, xb);
    k_router<<<NTOK / 4, 256, 0, stream>>>(x, gw, sel, selw, counts);
    k_scan<<<1, 64, 0, stream>>>(counts, basep, fillc);
    k_fill<<<NTOK / 256, 256, 0, stream>>>(sel, selw, basep, fillc, rowmap, rowk, roww);
    k_gemm1<<<dim3(FD / BN1, NTOK / BM, NE), 256, 0, stream>>>(xb, w1t, w3t, counts, basep, rowmap, act);
    k_gemm2<<<dim3(HD / BN, NTOK / BM2, NE * KS2), 256, 0, stream>>>(act, w2t, counts, basep, rowmap, rowk, roww, partial);
    k_combine<<<(NTOK * HD) / (256 * 4), 256, 0, stream>>>(partial, out);
}

// Round 11
// 330.321 us; speedup vs baseline: 1.0293x; 1.0008x over previous
//
#include <hip/hip_runtime.h>
#include <hip/hip_bf16.h>

#define NTOK 2048   // B*S
#define HD   1024
#define FD   3584
#define NE   8

#define BM 128              // gemm1 m-tile
#define BN1 64              // gemm1 f-tile
#define BM2 64              // gemm2 m-tile
#define BN 128              // gemm2 h-tile
#define BK 64               // 128B LDS rows (verified conflict-free layout)
#define NIT1 (HD / BK)      // 16
#define KS2 2               // gemm2 K-split
#define KLEN2 (FD / KS2)    // 1792
#define NIT2 (KLEN2 / BK)   // 28

typedef __attribute__((ext_vector_type(8))) short short8;
typedef __attribute__((ext_vector_type(4))) float f32x4;

__device__ __forceinline__ unsigned short f2bf(float f) {
    __hip_bfloat16 h = __float2bfloat16(f);
    union { __hip_bfloat16 h; unsigned short u; } c; c.h = h;
    return c.u;
}

// global_load_lds width=16: per-lane 16B global src -> wave-uniform LDS base + lane*16
typedef __attribute__((address_space(1))) const unsigned int g_cu32;
typedef __attribute__((address_space(3))) unsigned int l_u32;
__device__ __forceinline__ void gl16(const void* g, void* l) {
    __builtin_amdgcn_global_load_lds((g_cu32*)g, (l_u32*)(unsigned int)(size_t)l, 16, 0, 0);
}

// ---------------- router: fp32 logits, softmax, top-2, renorm ----------------
__global__ void k_router(const float* __restrict__ x, const float* __restrict__ gw,
                         int* __restrict__ sel, float* __restrict__ selw,
                         int* __restrict__ counts) {
    int token = blockIdx.x * 4 + (threadIdx.x >> 6);
    int lane  = threadIdx.x & 63;
    if (token >= NTOK) return;
    const float* xr = x + (size_t)token * HD;
    float acc[NE];
#pragma unroll
    for (int e = 0; e < NE; e++) acc[e] = 0.f;
    for (int h = lane; h < HD; h += 64) {
        float xv = xr[h];
        const float4* g = (const float4*)(gw + (size_t)h * NE);
        float4 g0 = g[0], g1 = g[1];
        acc[0] += xv * g0.x; acc[1] += xv * g0.y; acc[2] += xv * g0.z; acc[3] += xv * g0.w;
        acc[4] += xv * g1.x; acc[5] += xv * g1.y; acc[6] += xv * g1.z; acc[7] += xv * g1.w;
    }
#pragma unroll
    for (int e = 0; e < NE; e++) {
#pragma unroll
        for (int off = 32; off >= 1; off >>= 1) acc[e] += __shfl_xor(acc[e], off, 64);
    }
    if (lane == 0) {
        float m = acc[0];
#pragma unroll
        for (int e = 1; e < NE; e++) m = fmaxf(m, acc[e]);
        float z[NE];
#pragma unroll
        for (int e = 0; e < NE; e++) z[e] = expf(acc[e] - m);
        int e0 = 0; float z0 = z[0];
#pragma unroll
        for (int e = 1; e < NE; e++) if (z[e] > z0) { z0 = z[e]; e0 = e; }
        int e1 = -1; float z1 = -1.f;
#pragma unroll
        for (int e = 0; e < NE; e++) if (e != e0 && z[e] > z1) { z1 = z[e]; e1 = e; }
        float s = z0 + z1;
        sel[token * 2 + 0] = e0; sel[token * 2 + 1] = e1;
        selw[token * 2 + 0] = z0 / s; selw[token * 2 + 1] = z1 / s;
        atomicAdd(&counts[e0], 1);
        atomicAdd(&counts[e1], 1);
    }
}

__global__ void k_scan(const int* __restrict__ counts, int* __restrict__ basep,
                       int* __restrict__ fillc) {
    if (threadIdx.x == 0 && blockIdx.x == 0) {
        int b = 0;
        for (int e = 0; e < NE; e++) { basep[e] = b; b += counts[e]; fillc[e] = 0; }
    }
}

__global__ void k_fill(const int* __restrict__ sel, const float* __restrict__ selw,
                       const int* __restrict__ basep, int* __restrict__ fillc,
                       int* __restrict__ rowmap, int* __restrict__ rowk,
                       float* __restrict__ roww) {
    int n = blockIdx.x * blockDim.x + threadIdx.x;
    if (n >= NTOK) return;
#pragma unroll
    for (int k = 0; k < 2; k++) {
        int e = sel[n * 2 + k];
        int p = atomicAdd(&fillc[e], 1);
        int g = basep[e] + p;
        rowmap[g] = n; rowk[g] = k; roww[g] = selw[n * 2 + k];
    }
}

// ---------------- x -> bf16 ----------------
__global__ void k_cvt(const float* __restrict__ x, unsigned short* __restrict__ xb) {
    size_t i = ((size_t)blockIdx.x * blockDim.x + threadIdx.x) * 8;
    float4 a = *(const float4*)(x + i);
    float4 b = *(const float4*)(x + i + 4);
    unsigned short p[8] __attribute__((aligned(16))) =
        { f2bf(a.x), f2bf(a.y), f2bf(a.z), f2bf(a.w),
          f2bf(b.x), f2bf(b.y), f2bf(b.z), f2bf(b.w) };
    *(uint4*)(xb + i) = *(uint4*)p;
}

// ---------------- fused weight transpose+convert, pair-packed vector LDS ----------------
// z<8: w1 (K=HD,N=FD); z<16: w3; z>=16: w2 (K=FD,N=HD). 64x64 tile per block.
// Phase1: thread loads k-rows {2rp,2rp+1} x 8 cols (4 float4, coalesced), packs
// k-pairs into u32, 8 x ds_write_b32 into P[n][rp ^ ((n>>3)<<2)]  (2-way = free).
// Phase2: 2 x ds_read_b128 (quad 4(q^(n>>3)), contiguous+aligned under swizzle)
// + 2 x 16B global stores. Zero scalar LDS ops (old version: 16 ds_read_u16/thr).
__global__ void k_wt3(const float* __restrict__ w1, const float* __restrict__ w3,
                      const float* __restrict__ w2,
                      unsigned short* __restrict__ w1t, unsigned short* __restrict__ w3t,
                      unsigned short* __restrict__ w2t) {
    __shared__ unsigned int P[64 * 32];   // 8 KB pair layout: [n][32 k-pairs]
    const int z = blockIdx.z;
    int K, N, tx, ty;
    const float* src;
    unsigned short* dst;
    if (z < 16) {
        K = HD; N = FD;
        const int e = z & 7;
        src = (z < 8 ? w1 : w3) + (size_t)e * K * N;
        dst = (z < 8 ? w1t : w3t) + (size_t)e * N * K;
        tx = blockIdx.x % (FD / 64); ty = blockIdx.x / (FD / 64);
    } else {
        K = FD; N = HD;
        const int e = z - 16;
        src = w2 + (size_t)e * K * N;
        dst = w2t + (size_t)e * N * K;
        tx = blockIdx.x % (HD / 64); ty = blockIdx.x / (HD / 64);
    }
    src += (size_t)(ty * 64) * N + tx * 64;
    dst += (size_t)(tx * 64) * K + ty * 64;

    const int t = threadIdx.x;
    {
        const int rp = t >> 3;            // k-pair index 0..31
        const int c8 = t & 7;             // 8-col group
        const float* s0 = src + (size_t)(2 * rp) * N + c8 * 8;
        const float* s1 = s0 + N;
        float4 a0 = *(const float4*)(s0);
        float4 a1 = *(const float4*)(s0 + 4);
        float4 b0 = *(const float4*)(s1);
        float4 b1 = *(const float4*)(s1 + 4);
        float ev[8] = { a0.x, a0.y, a0.z, a0.w, a1.x, a1.y, a1.z, a1.w };
        float od[8] = { b0.x, b0.y, b0.z, b0.w, b1.x, b1.y, b1.z, b1.w };
#pragma unroll
        for (int j = 0; j < 8; j++) {
            const int n = c8 * 8 + j;
            unsigned int v = (unsigned int)f2bf(ev[j]) | ((unsigned int)f2bf(od[j]) << 16);
            P[n * 32 + (rp ^ ((n >> 3) << 2))] = v;
        }
    }
    __syncthreads();
    {
        const int n = t >> 2;             // output row (source col) 0..63
#pragma unroll
        for (int it = 0; it < 2; it++) {
            const int q = (t & 3) + 4 * it;   // k-octet 0..7
            uint4 v = *(const uint4*)&P[n * 32 + 4 * (q ^ (n >> 3))];
            *(uint4*)&dst[(size_t)n * K + q * 8] = v;
        }
    }
}

// ---------------- GEMM1: 256 thr, 4 waves 2x2, wave tile 64x32 ----------------
// LDS reads per kk: af[4]+b1f[2]+b3f[2] = 8 for 16 MFMAs (1:2).
// LDS 64KB dbuf -> 2 blocks/CU (8 waves). (256,2): no VGPR cap pressure.
__global__ __launch_bounds__(256, 2) void k_gemm1(
    const unsigned short* __restrict__ xb,
    const unsigned short* __restrict__ w1t, const unsigned short* __restrict__ w3t,
    const int* __restrict__ counts, const int* __restrict__ basep,
    const int* __restrict__ rowmap, unsigned short* __restrict__ act)
{
    const int e = blockIdx.z;
    const int nrows = counts[e];
    const int m0 = blockIdx.y * BM;
    if (m0 >= nrows) return;
    const int f0 = blockIdx.x * BN1;
    const int gbase = basep[e];

    __shared__ __align__(16) unsigned short At[2][BM][BK];
    __shared__ __align__(16) unsigned short B1[2][BN1][BK];
    __shared__ __align__(16) unsigned short B3[2][BN1][BK];

    const int t = threadIdx.x;
    const int lane = t & 63;
    const int w = t >> 6;                 // 0..3
    const int wrm = w >> 1, wnn = w & 1;  // 2x2 wave grid; wave tile 64 x 32
    const int lr = lane >> 3;
    const int so = ((lane & 7) ^ lr) * 8; // verified swizzle: chunk ^ (row&7)

    const unsigned short* asrc[4];
#pragma unroll
    for (int c = 0; c < 4; c++) {
        const int row = (w * 4 + c) * 8 + lr;
        const int tok = rowmap[gbase + min(m0 + row, nrows - 1)];
        asrc[c] = xb + (size_t)tok * HD + so;
    }
    const unsigned short* b1src[2];
    const unsigned short* b3src[2];
#pragma unroll
    for (int c = 0; c < 2; c++) {
        const int row = (w * 2 + c) * 8 + lr;
        b1src[c] = w1t + ((size_t)(e * FD + f0 + row)) * HD + so;
        b3src[c] = w3t + ((size_t)(e * FD + f0 + row)) * HD + so;
    }

    f32x4 acc1[4][2], acc3[4][2];
#pragma unroll
    for (int i = 0; i < 4; i++)
#pragma unroll
        for (int j = 0; j < 2; j++) { acc1[i][j] = (f32x4)(0.f); acc3[i][j] = (f32x4)(0.f); }

    const int l15 = lane & 15;
    const int lhi = lane >> 4;
    const int rs = (l15 & 7) * 8;

    // prologue: stage k-tile 0 into buf 0 (8 loads/thread in flight)
#pragma unroll
    for (int c = 0; c < 4; c++) gl16(asrc[c], &At[0][(w * 4 + c) * 8][0]);
#pragma unroll
    for (int c = 0; c < 2; c++) {
        gl16(b1src[c], &B1[0][(w * 2 + c) * 8][0]);
        gl16(b3src[c], &B3[0][(w * 2 + c) * 8][0]);
    }

    for (int it = 0; it < NIT1; ++it) {
        const int cur = it & 1;
        if (it + 1 < NIT1) {
            const int kn = (it + 1) * BK;
#pragma unroll
            for (int c = 0; c < 4; c++) gl16(asrc[c] + kn, &At[cur ^ 1][(w * 4 + c) * 8][0]);
#pragma unroll
            for (int c = 0; c < 2; c++) {
                gl16(b1src[c] + kn, &B1[cur ^ 1][(w * 2 + c) * 8][0]);
                gl16(b3src[c] + kn, &B3[cur ^ 1][(w * 2 + c) * 8][0]);
            }
            asm volatile("s_waitcnt vmcnt(8)" ::: "memory");   // wait current tile only
        } else {
            asm volatile("s_waitcnt vmcnt(0)" ::: "memory");
        }
        __builtin_amdgcn_s_barrier();
#pragma unroll
        for (int kk = 0; kk < 2; kk++) {
            const int kc = (kk * 32 + lhi * 8) ^ rs;
            short8 af[4], b1f[2], b3f[2];
#pragma unroll
            for (int i = 0; i < 4; i++)
                af[i] = *(const short8*)&At[cur][wrm * 64 + i * 16 + l15][kc];
#pragma unroll
            for (int j = 0; j < 2; j++) {
                b1f[j] = *(const short8*)&B1[cur][wnn * 32 + j * 16 + l15][kc];
                b3f[j] = *(const short8*)&B3[cur][wnn * 32 + j * 16 + l15][kc];
            }
#pragma unroll
            for (int i = 0; i < 4; i++)
#pragma unroll
                for (int j = 0; j < 2; j++) {
                    acc1[i][j] = __builtin_amdgcn_mfma_f32_16x16x32_bf16(af[i], b1f[j], acc1[i][j], 0, 0, 0);
                    acc3[i][j] = __builtin_amdgcn_mfma_f32_16x16x32_bf16(af[i], b3f[j], acc3[i][j], 0, 0, 0);
                }
        }
        __builtin_amdgcn_s_barrier();
    }

    // epilogue: SwiGLU, bf16 act
    const int rbase = wrm * 64 + lhi * 4;
    const int cbase = f0 + wnn * 32 + l15;
#pragma unroll
    for (int i = 0; i < 4; i++) {
#pragma unroll
        for (int r = 0; r < 4; r++) {
            const int ml = rbase + i * 16 + r;
            if (m0 + ml < nrows) {
                const size_t rowoff = (size_t)(gbase + m0 + ml) * FD;
#pragma unroll
                for (int j = 0; j < 2; j++) {
                    float y1 = acc1[i][j][r];
                    float y3 = acc3[i][j][r];
                    float sv = (y1 / (1.f + __expf(-y1))) * y3;
                    act[rowoff + cbase + j * 16] = f2bf(sv);
                }
            }
        }
    }
}

// ---------------- GEMM2: BM2=64 x BN=128, 256 thr, wave tile 32x64, K-split x2 ----------------
// LDS reads per kk: af[2]+bf[4] = 6 for 16 MFMAs (3:8). 48KB -> 3 blocks/CU.
__global__ __launch_bounds__(256, 4) void k_gemm2(
    const unsigned short* __restrict__ act,
    const unsigned short* __restrict__ w2t,
    const int* __restrict__ counts, const int* __restrict__ basep,
    const int* __restrict__ rowmap, const int* __restrict__ rowk,
    const float* __restrict__ roww, float* __restrict__ partial)
{
    const int z = blockIdx.z;
    const int e = z >> 1, ks = z & 1;
    const int nrows = counts[e];
    const int m0 = blockIdx.y * BM2;
    if (m0 >= nrows) return;
    const int h0 = blockIdx.x * BN;
    const int gbase = basep[e];
    const int kbase = ks * KLEN2;

    __shared__ __align__(16) unsigned short At[2][BM2][BK];
    __shared__ __align__(16) unsigned short Bt[2][BN][BK];

    const int t = threadIdx.x;
    const int lane = t & 63;
    const int w = t >> 6;                 // 0..3
    const int wr2 = w >> 1, wn2 = w & 1;  // 2x2; wave tile 32 x 64
    const int lr = lane >> 3;
    const int so = ((lane & 7) ^ lr) * 8;

    const unsigned short* asrc[2];
#pragma unroll
    for (int c = 0; c < 2; c++) {
        const int row = (w * 2 + c) * 8 + lr;
        asrc[c] = act + ((size_t)gbase + min(m0 + row, nrows - 1)) * FD + so + kbase;
    }
    const unsigned short* bsrc[4];
#pragma unroll
    for (int c = 0; c < 4; c++) {
        const int row = (w * 4 + c) * 8 + lr;
        bsrc[c] = w2t + ((size_t)(e * HD + h0 + row)) * FD + so + kbase;
    }

    f32x4 acc[2][4];
#pragma unroll
    for (int i = 0; i < 2; i++)
#pragma unroll
        for (int j = 0; j < 4; j++) acc[i][j] = (f32x4)(0.f);

    const int l15 = lane & 15;
    const int lhi = lane >> 4;
    const int rs = (l15 & 7) * 8;

    // prologue: stage tile 0 into buf 0 (6 loads/thread)
#pragma unroll
    for (int c = 0; c < 2; c++) gl16(asrc[c], &At[0][(w * 2 + c) * 8][0]);
#pragma unroll
    for (int c = 0; c < 4; c++) gl16(bsrc[c], &Bt[0][(w * 4 + c) * 8][0]);

    for (int it = 0; it < NIT2; ++it) {
        const int cur = it & 1;
        if (it + 1 < NIT2) {
            const int kn = (it + 1) * BK;
#pragma unroll
            for (int c = 0; c < 2; c++) gl16(asrc[c] + kn, &At[cur ^ 1][(w * 2 + c) * 8][0]);
#pragma unroll
            for (int c = 0; c < 4; c++) gl16(bsrc[c] + kn, &Bt[cur ^ 1][(w * 4 + c) * 8][0]);
            asm volatile("s_waitcnt vmcnt(6)" ::: "memory");
        } else {
            asm volatile("s_waitcnt vmcnt(0)" ::: "memory");
        }
        __builtin_amdgcn_s_barrier();
#pragma unroll
        for (int kk = 0; kk < 2; kk++) {
            const int kc = (kk * 32 + lhi * 8) ^ rs;
            short8 af[2], bf[4];
#pragma unroll
            for (int i = 0; i < 2; i++)
                af[i] = *(const short8*)&At[cur][wr2 * 32 + i * 16 + l15][kc];
#pragma unroll
            for (int j = 0; j < 4; j++)
                bf[j] = *(const short8*)&Bt[cur][wn2 * 64 + j * 16 + l15][kc];
#pragma unroll
            for (int i = 0; i < 2; i++)
#pragma unroll
                for (int j = 0; j < 4; j++)
                    acc[i][j] = __builtin_amdgcn_mfma_f32_16x16x32_bf16(af[i], bf[j], acc[i][j], 0, 0, 0);
        }
        __builtin_amdgcn_s_barrier();
    }

    const int rbase = wr2 * 32 + lhi * 4;
    const int cbase = h0 + wn2 * 64 + l15;
#pragma unroll
    for (int i = 0; i < 2; i++) {
#pragma unroll
        for (int r = 0; r < 4; r++) {
            const int ml = rbase + i * 16 + r;
            if (m0 + ml < nrows) {
                const int grow = gbase + m0 + ml;
                const int tok = rowmap[grow];
                const int slot = rowk[grow];
                const float wv = roww[grow];
                float* op = partial + (((size_t)slot * KS2 + ks) * NTOK + tok) * HD + cbase;
#pragma unroll
                for (int j = 0; j < 4; j++) op[j * 16] = acc[i][j][r] * wv;
            }
        }
    }
}

__global__ void k_combine(const float* __restrict__ partial, float* __restrict__ out) {
    size_t i = ((size_t)blockIdx.x * blockDim.x + threadIdx.x) * 4;
    const size_t st = (size_t)NTOK * HD;
    float4 o = *(const float4*)(partial + i);
#pragma unroll
    for (int s = 1; s < 2 * KS2; s++) {
        float4 v = *(const float4*)(partial + (size_t)s * st + i);
        o.x += v.x; o.y += v.y; o.z += v.z; o.w += v.w;
    }
    *(float4*)(out + i) = o;
}

extern "C" void kernel_launch(void* const* d_in, const int* in_sizes, int n_in,
                              void* d_out, int out_size, void* d_ws, size_t ws_size,
                              hipStream_t stream) {
    const float* x  = (const float*)d_in[0];
    const float* gw = (const float*)d_in[1];
    const float* w1 = (const float*)d_in[2];
    const float* w3 = (const float*)d_in[3];
    const float* w2 = (const float*)d_in[4];
    float* out = (float*)d_out;

    char* ws = (char*)d_ws;
    size_t off = 0;
    auto alloc = [&](size_t b) { char* p = ws + off; off += (b + 255) & ~(size_t)255; return p; };
    int*   sel    = (int*)  alloc((size_t)NTOK * 2 * 4);
    float* selw   = (float*)alloc((size_t)NTOK * 2 * 4);
    int*   counts = (int*)  alloc(NE * 4);
    int*   basep  = (int*)  alloc(NE * 4);
    int*   fillc  = (int*)  alloc(NE * 4);
    int*   rowmap = (int*)  alloc((size_t)NTOK * 2 * 4);
    int*   rowk   = (int*)  alloc((size_t)NTOK * 2 * 4);
    float* roww   = (float*)alloc((size_t)NTOK * 2 * 4);
    unsigned short* xb  = (unsigned short*)alloc((size_t)NTOK * HD * 2);
    unsigned short* act = (unsigned short*)alloc((size_t)NTOK * 2 * FD * 2);
    unsigned short* w1t = (unsigned short*)alloc((size_t)NE * HD * FD * 2);
    unsigned short* w3t = (unsigned short*)alloc((size_t)NE * HD * FD * 2);
    unsigned short* w2t = (unsigned short*)alloc((size_t)NE * HD * FD * 2);
    // partial (2*KS2=4 x NTOK x HD f32 = 33.6 MB) aliases w1t's region (58.7 MB):
    // w1t is dead after k_gemm1; partial is written in k_gemm2, read in k_combine.
    float* partial = (float*)w1t;

    hipMemsetAsync(counts, 0, NE * 4, stream);
    k_wt3<<<dim3(896, 1, 24), 256, 0, stream>>>(w1, w3, w2, w1t, w3t, w2t);
    k_cvt<<<(NTOK * HD) / (256 * 8), 256, 0, stream>>>(x, xb);
    k_router<<<NTOK / 4, 256, 0, stream>>>(x, gw, sel, selw, counts);
    k_scan<<<1, 64, 0, stream>>>(counts, basep, fillc);
    k_fill<<<NTOK / 256, 256, 0, stream>>>(sel, selw, basep, fillc, rowmap, rowk, roww);
    k_gemm1<<<dim3(FD / BN1, NTOK / BM, NE), 256, 0, stream>>>(xb, w1t, w3t, counts, basep, rowmap, act);
    k_gemm2<<<dim3(HD / BN, NTOK / BM2, NE * KS2), 256, 0, stream>>>(act, w2t, counts, basep, rowmap, rowk, roww, partial);
    k_combine<<<(NTOK * HD) / (256 * 4), 256, 0, stream>>>(partial, out);
}